// Round 2
// 615.009 us; speedup vs baseline: 1.0333x; 1.0333x over previous
//
#include <hip/hip_runtime.h>
#include <hip/hip_bf16.h>

// LoRA linear: out = x @ (W.T + (alpha/rank) * B@A) + bias
// x: [65536, 1024] f32, W: [1024,1024] f32 ([out,in]), bias: [1024] f32,
// B: [1024,16] f32, A: [16,1024] f32. out: [65536,1024] f32.
// Kernel 1 builds WeffT[n][k] bf16 in d_ws (unchanged).
// Kernel 2: 256x256 tile, 8 waves, double-buffered 128 KiB LDS, counted-vmcnt
// pipeline (T3+T4), XOR bank swizzle (T2), setprio (T5), XCD swizzle (T1).

typedef short short8 __attribute__((ext_vector_type(8)));   // 8 bf16 = 4 VGPRs
typedef float f32x4 __attribute__((ext_vector_type(4)));

#define K_DIM 1024
#define N_DIM 1024
#define BM 256
#define BN 256
#define BK 64
#define NT (K_DIM / BK)   // 16 K-steps

static __device__ __forceinline__ unsigned short f2bf_rne(float v) {
    unsigned u = __builtin_bit_cast(unsigned, v);
    u += 0x7fffu + ((u >> 16) & 1u);
    return (unsigned short)(u >> 16);
}

static __device__ __forceinline__ int pack_bf16x2(float a, float b) {
    __hip_bfloat162 h = __float22bfloat162_rn(make_float2(a, b));  // v_cvt_pk_bf16_f32 (RNE)
    int r;
    __builtin_memcpy(&r, &h, sizeof(r));
    return r;
}

// ---------------- Kernel 1: effective weight (transposed, bf16) ----------------
__global__ __launch_bounds__(256) void weff_kernel(
    const float* __restrict__ W, const float* __restrict__ B,
    const float* __restrict__ A, unsigned short* __restrict__ WeffT) {
    int idx = blockIdx.x * 256 + threadIdx.x;   // n*1024 + k
    int n = idx >> 10;
    int k = idx & 1023;
    const float4* Bk = (const float4*)(B + k * 16);
    float s = 0.f;
#pragma unroll
    for (int r4 = 0; r4 < 4; ++r4) {
        float4 b4 = Bk[r4];
        s += b4.x * A[(r4 * 4 + 0) * N_DIM + n];
        s += b4.y * A[(r4 * 4 + 1) * N_DIM + n];
        s += b4.z * A[(r4 * 4 + 2) * N_DIM + n];
        s += b4.w * A[(r4 * 4 + 3) * N_DIM + n];
    }
    float v = W[idx] + 2.0f * s;
    WeffT[idx] = f2bf_rne(v);
}

// ---------------- Kernel 2: pipelined GEMM C = X @ WeffT^T + bias ----------------
__global__ __launch_bounds__(512, 2) void lora_gemm(
    const float* __restrict__ X, const unsigned short* __restrict__ WeffT,
    const float* __restrict__ bias, float* __restrict__ Out) {
    __shared__ short As[2][BM * BK];   // 2 x 32 KiB
    __shared__ short Bs[2][BN * BK];   // 2 x 32 KiB  -> 128 KiB total

    const int t = threadIdx.x;
    const int lane = t & 63;
    const int w = t >> 6;        // wave 0..7
    const int quad = lane >> 4;  // 0..3
    const int l15 = lane & 15;
    const int wm = w >> 2;       // 0..1  (M waves)
    const int wc = w & 3;        // 0..3  (N waves)

    // Bijective XCD swizzle: nwg = 1024 = 8 * 128. n_tile fastest so the 4
    // blocks sharing an X panel run concurrently on one XCD (L2 reuse of X).
    const int bid = blockIdx.x;
    const int wgid = (bid & 7) * 128 + (bid >> 3);
    const int m_tile = wgid >> 2;      // 0..255
    const int n_tile = wgid & 3;       // 0..3
    const size_t m_base = (size_t)m_tile * BM;
    const int n_base = n_tile * BN;

    // --- staging geometry: 2048 16B-chunks per tile, thread owns slots i*512+t ---
    const int trow = t >> 3;                 // row within 64-row stripe
    const int tc = t & 7;                    // 16B chunk within row
    const int tswz = tc ^ (trow & 7);        // XOR bank swizzle (T2)
    const float* asrc0 = X + (m_base + trow) * K_DIM + tc * 8;
    const unsigned short* bsrc0 = WeffT + (size_t)(n_base + trow) * K_DIM + tswz * 8;
    const int aw_base = trow * BK + tswz * 8;      // shorts, +i*4096 per stripe

    // --- fragment read bases (row & 7 == l15 & 7 for all frag rows) ---
    const int a_base = (wm * 128 + l15) * BK;      // + mi*1024 + sw
    const int b_base = (wc * 64 + l15) * BK;       // + ni*1024 + sw
    const int sw0 = (quad ^ (l15 & 7)) * 8;        // kc=0 chunk, swizzled
    const int sw1 = ((4 + quad) ^ (l15 & 7)) * 8;  // kc=1 chunk, swizzled

    f32x4 acc[8][4];
#pragma unroll
    for (int mi = 0; mi < 8; ++mi)
#pragma unroll
        for (int ni = 0; ni < 4; ++ni)
            acc[mi][ni] = (f32x4){0.f, 0.f, 0.f, 0.f};

    f32x4 rA[8];   // in-flight X f32 (one K-step, 32 VGPR)

#define ISSUE_B(pp, koff)                                                           \
    do {                                                                            \
        _Pragma("unroll") for (int i = 0; i < 4; ++i) {                             \
            __builtin_amdgcn_global_load_lds(                                       \
                (const __attribute__((address_space(1))) unsigned int*)(            \
                    bsrc0 + i * 64 * K_DIM + (koff)),                               \
                (__attribute__((address_space(3))) unsigned int*)                   \
                    &Bs[pp][w * 512 + i * 4096],                                    \
                16, 0, 0);                                                          \
        }                                                                           \
    } while (0)

#define ISSUE_A(koff)                                                               \
    do {                                                                            \
        _Pragma("unroll") for (int i = 0; i < 4; ++i) {                             \
            const f32x4* gp = (const f32x4*)(asrc0 + i * 64 * K_DIM + (koff));      \
            rA[2 * i] = gp[0];                                                      \
            rA[2 * i + 1] = gp[1];                                                  \
        }                                                                           \
    } while (0)

#define CVT_WRITE(pp)                                                               \
    do {                                                                            \
        _Pragma("unroll") for (int i = 0; i < 4; ++i) {                             \
            int4 wv;                                                                \
            wv.x = pack_bf16x2(rA[2 * i][0], rA[2 * i][1]);                         \
            wv.y = pack_bf16x2(rA[2 * i][2], rA[2 * i][3]);                         \
            wv.z = pack_bf16x2(rA[2 * i + 1][0], rA[2 * i + 1][1]);                 \
            wv.w = pack_bf16x2(rA[2 * i + 1][2], rA[2 * i + 1][3]);                 \
            *(int4*)&As[pp][aw_base + i * 4096] = wv;                               \
        }                                                                           \
    } while (0)

#define COMPUTE(pp, swv)                                                            \
    do {                                                                            \
        short8 af[8], bf[4];                                                        \
        _Pragma("unroll") for (int mi = 0; mi < 8; ++mi)                            \
            af[mi] = *(const short8*)&As[pp][a_base + mi * 1024 + (swv)];           \
        _Pragma("unroll") for (int ni = 0; ni < 4; ++ni)                            \
            bf[ni] = *(const short8*)&Bs[pp][b_base + ni * 1024 + (swv)];           \
        __builtin_amdgcn_s_setprio(1);                                              \
        _Pragma("unroll") for (int mi = 0; mi < 8; ++mi)                            \
            _Pragma("unroll") for (int ni = 0; ni < 4; ++ni)                        \
                acc[mi][ni] = __builtin_amdgcn_mfma_f32_16x16x32_bf16(              \
                    af[mi], bf[ni], acc[mi][ni], 0, 0, 0);                          \
        __builtin_amdgcn_s_setprio(0);                                              \
    } while (0)

    // ---- prologue: fill buffer 0, start A(1) in flight ----
    ISSUE_B(0, 0);
    ISSUE_A(0);
    asm volatile("s_waitcnt vmcnt(0)" ::: "memory");
    CVT_WRITE(0);
    ISSUE_A(BK);                       // A for step 1 rides across the barrier
    asm volatile("s_waitcnt lgkmcnt(0)" ::: "memory");
    __builtin_amdgcn_s_barrier();

    // ---- main loop: 1 barrier per K-step, counted vmcnt (never 0 mid-loop) ----
    // Invariant at step s entry: Abuf/Bbuf[s&1] ready; A(s+1) f32 in rA-flight.
#pragma unroll 2
    for (int s = 0; s < NT; ++s) {
        const int p = s & 1;
        if (s + 1 < NT) ISSUE_B(p ^ 1, (s + 1) * BK);   // B DMA for next step
        COMPUTE(p, sw0);                                 // 32 MFMA, kc=0
        if (s + 1 < NT) {
            // retire A(s+1) (oldest 8), leave B(s+1) DMA (4) in flight
            asm volatile("s_waitcnt vmcnt(4)" ::: "memory");
            CVT_WRITE(p ^ 1);                            // bf16 -> As[next]
            if (s + 2 < NT) ISSUE_A((s + 2) * BK);       // A two steps ahead
        }
        COMPUTE(p, sw1);                                 // 32 MFMA, kc=1
        if (s + 1 < NT) {
            if (s + 2 < NT)   // retire B(s+1); A(s+2)'s 8 loads stay in flight
                asm volatile("s_waitcnt vmcnt(8) lgkmcnt(0)" ::: "memory");
            else              // pipeline tail: nothing younger, drain
                asm volatile("s_waitcnt vmcnt(0) lgkmcnt(0)" ::: "memory");
            __builtin_amdgcn_s_barrier();
        }
    }

#undef ISSUE_B
#undef ISSUE_A
#undef CVT_WRITE
#undef COMPUTE

    // ---- epilogue: C/D layout col=lane&15, row=quad*4+reg ----
#pragma unroll
    for (int ni = 0; ni < 4; ++ni) {
        const int col = n_base + wc * 64 + ni * 16 + l15;
        const float bv = bias[col];
#pragma unroll
        for (int mi = 0; mi < 8; ++mi) {
            const size_t row0 = m_base + wm * 128 + mi * 16 + quad * 4;
#pragma unroll
            for (int r = 0; r < 4; ++r)
                Out[(row0 + r) * N_DIM + col] = acc[mi][ni][r] + bv;
        }
    }
}

extern "C" void kernel_launch(void* const* d_in, const int* in_sizes, int n_in,
                              void* d_out, int out_size, void* d_ws, size_t ws_size,
                              hipStream_t stream) {
    const float* x    = (const float*)d_in[0];
    const float* W    = (const float*)d_in[1];
    const float* bias = (const float*)d_in[2];
    const float* B    = (const float*)d_in[3];
    const float* A    = (const float*)d_in[4];
    float* out = (float*)d_out;
    unsigned short* WeffT = (unsigned short*)d_ws;  // 1024*1024 bf16 = 2 MB

    weff_kernel<<<4096, 256, 0, stream>>>(W, B, A, WeffT);

    int M = out_size / N_DIM;            // 65536
    int grid = (M / BM) * (N_DIM / BN);  // 256 * 4 = 1024
    lora_gemm<<<grid, 512, 0, stream>>>(x, WeffT, bias, out);
}

// Round 3
// 614.920 us; speedup vs baseline: 1.0335x; 1.0001x over previous
//
#include <hip/hip_runtime.h>
#include <hip/hip_bf16.h>

// LoRA linear: out = x @ (W.T + (alpha/rank) * B@A) + bias
// Kernel 1 builds WeffT[n][k] bf16 in d_ws (unchanged).
// Kernel 2: 256x256 tile, BK=64, 8 waves, 2x2 half-tile double-buffer (128 KiB),
// m201-style 8-phase schedule: per phase {stage | 12 ds_read | lgkm0 | bar |
// setprio MFMA x16 | bar}, counted vmcnt(4) only at phases 3/7 BEFORE the
// phase-ending barrier (cross-wave DMA visibility). A reg-staged (T14, f32->
// cvt_pk->ds_write), B via global_load_lds with pre-swizzled source (T2).

typedef short short8 __attribute__((ext_vector_type(8)));   // 8 bf16 = 4 VGPRs
typedef float f32x4 __attribute__((ext_vector_type(4)));

#define K_DIM 1024
#define N_DIM 1024
#define BM 256
#define BN 256
#define BK 64

static __device__ __forceinline__ unsigned short f2bf_rne(float v) {
    unsigned u = __builtin_bit_cast(unsigned, v);
    u += 0x7fffu + ((u >> 16) & 1u);
    return (unsigned short)(u >> 16);
}

static __device__ __forceinline__ int pack_bf16x2(float a, float b) {
    __hip_bfloat162 h = __float22bfloat162_rn(make_float2(a, b));  // v_cvt_pk_bf16_f32
    int r;
    __builtin_memcpy(&r, &h, sizeof(r));
    return r;
}

// ---------------- Kernel 1: effective weight (transposed, bf16) ----------------
__global__ __launch_bounds__(256) void weff_kernel(
    const float* __restrict__ W, const float* __restrict__ B,
    const float* __restrict__ A, unsigned short* __restrict__ WeffT) {
    int idx = blockIdx.x * 256 + threadIdx.x;   // n*1024 + k
    int n = idx >> 10;
    int k = idx & 1023;
    const float4* Bk = (const float4*)(B + k * 16);
    float s = 0.f;
#pragma unroll
    for (int r4 = 0; r4 < 4; ++r4) {
        float4 b4 = Bk[r4];
        s += b4.x * A[(r4 * 4 + 0) * N_DIM + n];
        s += b4.y * A[(r4 * 4 + 1) * N_DIM + n];
        s += b4.z * A[(r4 * 4 + 2) * N_DIM + n];
        s += b4.w * A[(r4 * 4 + 3) * N_DIM + n];
    }
    float v = W[idx] + 2.0f * s;
    WeffT[idx] = f2bf_rne(v);
}

// ---------------- Kernel 2: 8-phase pipelined GEMM ----------------
__global__ __launch_bounds__(512, 2) void lora_gemm(
    const float* __restrict__ X, const unsigned short* __restrict__ WeffT,
    const float* __restrict__ bias, float* __restrict__ Out) {
    // [buf][half][128 rows x 64 k] bf16; 4 x 16 KiB each matrix -> 128 KiB total
    __shared__ short As[2][2][128 * 64];
    __shared__ short Bs[2][2][128 * 64];

    const int t = threadIdx.x;
    const int lane = t & 63;
    const int w = t >> 6;        // wave 0..7
    const int quad = lane >> 4;  // 0..3
    const int l15 = lane & 15;
    const int wm = w >> 2;       // 0..1 -> A-half (M)
    const int wc = w & 3;        // 0..3
    const int bh = wc >> 1;      // B-half (N)

    // Bijective XCD swizzle: nwg=1024=8*128; n_tile fastest for X L2 reuse.
    const int bid = blockIdx.x;
    const int wgid = (bid & 7) * 128 + (bid >> 3);
    const int m_tile = wgid >> 2;      // 0..255
    const int n_tile = wgid & 3;       // 0..3
    const size_t m_base = (size_t)m_tile * BM;
    const int n_base = n_tile * BN;

    // staging geometry: thread -> (row-in-64-stripe, 16B chunk)
    const int trow = t >> 3;                   // 0..63
    const int tc = t & 7;                      // 0..7
    const int awc = (tc ^ (trow & 7)) * 8;     // swizzled write chunk (shorts)
    const float* asrc_base = X + (m_base + trow) * K_DIM + tc * 8;
    const unsigned short* bsrc_base =
        WeffT + (size_t)(n_base + trow) * K_DIM + (size_t)(tc ^ (trow & 7)) * 8;

    // fragment read offsets (row&7 == l15&7 for all fragment rows)
    const int sw0 = (quad ^ (l15 & 7)) * 8;
    const int sw1 = ((4 + quad) ^ (l15 & 7)) * 8;
    const int a_off0 = l15 * 64 + sw0;
    const int a_off1 = l15 * 64 + sw1;
    const int b_off0 = (wc & 1) * 4096 + l15 * 64 + sw0;
    const int b_off1 = (wc & 1) * 4096 + l15 * 64 + sw1;

    f32x4 acc[8][4];
#pragma unroll
    for (int mi = 0; mi < 8; ++mi)
#pragma unroll
        for (int ni = 0; ni < 4; ++ni)
            acc[mi][ni] = (f32x4){0.f, 0.f, 0.f, 0.f};

    f32x4 rA[8];   // in-flight X f32: rA[0..3]=half0, rA[4..7]=half1

#define FENCE asm volatile("" ::: "memory")

// issue 2 global_load_lds (one B half-tile slice), 16B/lane, linear LDS dest
#define ISSUE_B(PB, H, koff)                                                        \
    do {                                                                            \
        _Pragma("unroll") for (int j = 0; j < 2; ++j) {                             \
            __builtin_amdgcn_global_load_lds(                                       \
                (const __attribute__((address_space(1))) unsigned int*)(            \
                    bsrc_base + (size_t)((H) * 128 + j * 64) * K_DIM + (koff)),     \
                (__attribute__((address_space(3))) unsigned int*)                   \
                    &Bs[PB][H][(j * 512 + w * 64) * 8],                             \
                16, 0, 0);                                                          \
        }                                                                           \
    } while (0)

// issue 4 f32x4 loads of one A half-tile into rA[H*4 .. H*4+3]
#define ISSUE_A(H, koff)                                                            \
    do {                                                                            \
        _Pragma("unroll") for (int i = 0; i < 2; ++i) {                             \
            const f32x4* gp = (const f32x4*)(asrc_base +                            \
                (size_t)((H) * 128 + i * 64) * K_DIM + (koff));                     \
            rA[(H) * 4 + 2 * i] = gp[0];                                            \
            rA[(H) * 4 + 2 * i + 1] = gp[1];                                        \
        }                                                                           \
    } while (0)

// cvt rA[H*4..] -> bf16, swizzled ds_write into As[PB][H] (compiler inserts
// the exact vmcnt for the rA dependency)
#define CVT_WRITE(PB, H)                                                            \
    do {                                                                            \
        _Pragma("unroll") for (int i = 0; i < 2; ++i) {                             \
            int4 wv;                                                                \
            wv.x = pack_bf16x2(rA[(H)*4 + 2*i][0], rA[(H)*4 + 2*i][1]);             \
            wv.y = pack_bf16x2(rA[(H)*4 + 2*i][2], rA[(H)*4 + 2*i][3]);             \
            wv.z = pack_bf16x2(rA[(H)*4 + 2*i + 1][0], rA[(H)*4 + 2*i + 1][1]);     \
            wv.w = pack_bf16x2(rA[(H)*4 + 2*i + 1][2], rA[(H)*4 + 2*i + 1][3]);     \
            *(int4*)&As[PB][H][(i * 64 + trow) * 64 + awc] = wv;                    \
        }                                                                           \
    } while (0)

// one phase: 12 ds_read (quadrant MH,NH of buf PB) | lgkm0 | bar | 16 MFMA
#define PHASE_CORE(PB, MH, NH)                                                      \
    do {                                                                            \
        short8 af0[4], af1[4], bf0[2], bf1[2];                                      \
        _Pragma("unroll") for (int mi = 0; mi < 4; ++mi) {                          \
            af0[mi] = *(const short8*)&As[PB][wm][(MH)*4096 + mi*1024 + a_off0];    \
            af1[mi] = *(const short8*)&As[PB][wm][(MH)*4096 + mi*1024 + a_off1];    \
        }                                                                           \
        _Pragma("unroll") for (int ni = 0; ni < 2; ++ni) {                          \
            bf0[ni] = *(const short8*)&Bs[PB][bh][(NH)*2048 + ni*1024 + b_off0];    \
            bf1[ni] = *(const short8*)&Bs[PB][bh][(NH)*2048 + ni*1024 + b_off1];    \
        }                                                                           \
        asm volatile("s_waitcnt lgkmcnt(0)" ::: "memory");                          \
        __builtin_amdgcn_sched_barrier(0);                                          \
        __builtin_amdgcn_s_barrier();                                               \
        __builtin_amdgcn_s_setprio(1);                                              \
        _Pragma("unroll") for (int mi = 0; mi < 4; ++mi)                            \
            _Pragma("unroll") for (int ni = 0; ni < 2; ++ni) {                      \
                acc[(MH)*4+mi][(NH)*2+ni] = __builtin_amdgcn_mfma_f32_16x16x32_bf16(\
                    af0[mi], bf0[ni], acc[(MH)*4+mi][(NH)*2+ni], 0, 0, 0);          \
                acc[(MH)*4+mi][(NH)*2+ni] = __builtin_amdgcn_mfma_f32_16x16x32_bf16(\
                    af1[mi], bf1[ni], acc[(MH)*4+mi][(NH)*2+ni], 0, 0, 0);          \
            }                                                                       \
        __builtin_amdgcn_s_setprio(0);                                              \
    } while (0)

#define PHASE_END __builtin_amdgcn_s_barrier()
#define GATE4 do { asm volatile("s_waitcnt vmcnt(4)" ::: "memory"); \
                   __builtin_amdgcn_sched_barrier(0); } while (0)
#define GATE0 do { asm volatile("s_waitcnt vmcnt(0)" ::: "memory"); \
                   __builtin_amdgcn_sched_barrier(0); } while (0)

    // ---- prologue: tile0 -> buf0 (staged), tile1 A-loads in flight ----
    // Issue order establishes the steady queue [B2, A4, B2, A4].
    ISSUE_A(0, 0);            // t0 h0 -> rA[0..3]
    ISSUE_A(1, 0);            // t0 h1 -> rA[4..7]
    FENCE;
    ISSUE_B(0, 0, 0);         // B(t0,h0)
    FENCE;
    CVT_WRITE(0, 0);          // As[0][0] <- t0 h0
    FENCE;
    ISSUE_A(0, 64);           // t1 h0 -> rA[0..3]
    FENCE;
    CVT_WRITE(0, 1);          // As[0][1] <- t0 h1
    FENCE;
    ISSUE_B(0, 1, 0);         // B(t0,h1)
    FENCE;
    ISSUE_A(1, 64);           // t1 h1 -> rA[4..7]
    FENCE;
    GATE4;                    // B(t0,h0), A(t1,h0), B(t0,h1) retired
    asm volatile("s_waitcnt lgkmcnt(0)" ::: "memory");
    __builtin_amdgcn_sched_barrier(0);
    __builtin_amdgcn_s_barrier();

    // ---- main loop: iter u computes tiles 2u (buf0, p0-3) and 2u+1 (buf1, p4-7)
    // stages tile 2u+1 -> buf1 at p0-1, tile 2u+2 -> buf0 at p4-5,
    // A-loads for 2u+2 at p0-1, for 2u+3 at p4-5.
#pragma unroll 1
    for (int u = 0; u < 7; ++u) {
        const int kt = u * 128;
        // p0
        CVT_WRITE(1, 0); FENCE; ISSUE_B(1, 0, kt + 64); FENCE; ISSUE_A(0, kt + 128); FENCE;
        PHASE_CORE(0, 0, 0); PHASE_END;
        // p1
        CVT_WRITE(1, 1); FENCE; ISSUE_B(1, 1, kt + 64); FENCE; ISSUE_A(1, kt + 128); FENCE;
        PHASE_CORE(0, 0, 1); PHASE_END;
        // p2
        PHASE_CORE(0, 1, 0); PHASE_END;
        // p3: gate buf1's B-DMA before the barrier (cross-wave visibility)
        PHASE_CORE(0, 1, 1); GATE4; PHASE_END;
        // p4
        CVT_WRITE(0, 0); FENCE; ISSUE_B(0, 0, kt + 128); FENCE; ISSUE_A(0, kt + 192); FENCE;
        PHASE_CORE(1, 0, 0); PHASE_END;
        // p5
        CVT_WRITE(0, 1); FENCE; ISSUE_B(0, 1, kt + 128); FENCE; ISSUE_A(1, kt + 192); FENCE;
        PHASE_CORE(1, 0, 1); PHASE_END;
        // p6
        PHASE_CORE(1, 1, 0); PHASE_END;
        // p7: gate buf0's B-DMA for next iter p0
        PHASE_CORE(1, 1, 1); GATE4; PHASE_END;
    }

    // ---- tail iteration u=7: tiles 14 (buf0), 15 (buf1); no loads past K ----
    {
        CVT_WRITE(1, 0); FENCE; ISSUE_B(1, 0, 960); FENCE;
        PHASE_CORE(0, 0, 0); PHASE_END;
        CVT_WRITE(1, 1); FENCE; ISSUE_B(1, 1, 960); FENCE;
        PHASE_CORE(0, 0, 1); PHASE_END;
        PHASE_CORE(0, 1, 0); PHASE_END;
        PHASE_CORE(0, 1, 1); GATE0; PHASE_END;
        PHASE_CORE(1, 0, 0); PHASE_END;
        PHASE_CORE(1, 0, 1); PHASE_END;
        PHASE_CORE(1, 1, 0); PHASE_END;
        PHASE_CORE(1, 1, 1);     // last MFMA cluster; no trailing barrier needed
    }

#undef FENCE
#undef ISSUE_B
#undef ISSUE_A
#undef CVT_WRITE
#undef PHASE_CORE
#undef PHASE_END
#undef GATE4
#undef GATE0

    // ---- epilogue: C/D layout col=lane&15, row=quad*4+reg ----
#pragma unroll
    for (int ni = 0; ni < 4; ++ni) {
        const int col = n_base + wc * 64 + ni * 16 + l15;
        const float bv = bias[col];
#pragma unroll
        for (int mi = 0; mi < 8; ++mi) {
            const size_t row0 = m_base + wm * 128 + mi * 16 + quad * 4;
#pragma unroll
            for (int r = 0; r < 4; ++r)
                Out[(row0 + r) * N_DIM + col] = acc[mi][ni][r] + bv;
        }
    }
}

extern "C" void kernel_launch(void* const* d_in, const int* in_sizes, int n_in,
                              void* d_out, int out_size, void* d_ws, size_t ws_size,
                              hipStream_t stream) {
    const float* x    = (const float*)d_in[0];
    const float* W    = (const float*)d_in[1];
    const float* bias = (const float*)d_in[2];
    const float* B    = (const float*)d_in[3];
    const float* A    = (const float*)d_in[4];
    float* out = (float*)d_out;
    unsigned short* WeffT = (unsigned short*)d_ws;  // 1024*1024 bf16 = 2 MB

    weff_kernel<<<4096, 256, 0, stream>>>(W, B, A, WeffT);

    int M = out_size / N_DIM;            // 65536
    int grid = (M / BM) * (N_DIM / BN);  // 256 * 4 = 1024
    lora_gemm<<<grid, 512, 0, stream>>>(x, WeffT, bias, out);
}